// Round 1
// baseline (183.094 us; speedup 1.0000x reference)
//
#include <hip/hip_runtime.h>

using short8 = __attribute__((ext_vector_type(8))) short;
using f32x4  = __attribute__((ext_vector_type(4))) float;

#define HD 128
#define NN 256
#define TS 136  // LDS tile row stride in ushorts (128 + 8 pad)

__device__ __forceinline__ unsigned short f2bf(float x) {
    union { float f; unsigned int u; } c; c.f = x;
    unsigned int u = c.u;
    unsigned int r = (u + 0x7FFFu + ((u >> 16) & 1u)) >> 16;
    return (unsigned short)r;
}
__device__ __forceinline__ unsigned int pk2(float a, float b) {
    return (unsigned int)f2bf(a) | ((unsigned int)f2bf(b) << 16);
}
__device__ __forceinline__ float silu(float v) {
    return v / (1.f + __expf(-v));
}

// ---- prep: A_pre = h @ we1[0:D] + be1 ; B_pre = h @ we1[D:2D] ----
__global__ __launch_bounds__(128) void prep_node(
    const float* __restrict__ h, const float* __restrict__ we1,
    const float* __restrict__ be1, float* __restrict__ Apre, float* __restrict__ Bpre)
{
    const int bn = blockIdx.x;      // 0..2047
    const int t  = threadIdx.x;     // h-col 0..127
    __shared__ float hs[HD];
    hs[t] = h[bn * HD + t];
    __syncthreads();
    float a = be1[t], bb = 0.f;
    #pragma unroll 4
    for (int d = 0; d < HD; ++d) {
        const float hv = hs[d];
        a  += hv * we1[d * HD + t];
        bb += hv * we1[(HD + d) * HD + t];
    }
    Apre[bn * HD + t] = a;
    Bpre[bn * HD + t] = bb;
}

// ---- prep: pack 128x128 fp32 weight -> bf16, k-contiguous per MFMA B-fragment ----
// pk[(k>>3)*128*8 + n*8 + (k&7)] = bf16(w[k][n])
__global__ __launch_bounds__(256) void prep_pack(
    const float* __restrict__ w, unsigned short* __restrict__ pk)
{
    const int idx = blockIdx.x * 256 + threadIdx.x;   // 0..16383
    const int k = idx >> 7, n = idx & 127;
    pk[((k >> 3) * 128 + n) * 8 + (k & 7)] = f2bf(w[idx]);
}

// ---- main: one block per (b,i) ----
__global__ __launch_bounds__(256) void egcl_main(
    const float* __restrict__ h, const float* __restrict__ x,
    const int* __restrict__ mask, const float* __restrict__ we1,
    const float* __restrict__ be2, const float* __restrict__ bc1,
    const float* __restrict__ wc2,
    const float* __restrict__ wn1, const float* __restrict__ bn1,
    const float* __restrict__ wn2, const float* __restrict__ bn2,
    const float* __restrict__ gamma, const float* __restrict__ beta,
    const float* __restrict__ Apre, const float* __restrict__ Bpre,
    const unsigned short* __restrict__ we2pk, const unsigned short* __restrict__ wc1pk,
    float* __restrict__ hout, float* __restrict__ xout)
{
    const int blk  = blockIdx.x;
    const int b    = blk >> 8, i = blk & 255;
    const int tid  = threadIdx.x;
    const int wv   = tid >> 6, lane = tid & 63;
    const int g    = lane >> 4, cl = lane & 15;

    __shared__ __align__(16) unsigned short tile[64 * TS];
    __shared__ float maskf_s[NN];
    __shared__ __align__(16) float Ai_s[HD], wlast_s[HD];
    __shared__ float wc2_s[HD], be2_s[HD], bc1_s[HD], hi_s[HD], s4_s[HD], agg_s[HD];
    __shared__ float d2_s[64];
    __shared__ float xj_s[64][3];
    __shared__ float sws[4][64];
    __shared__ float cd_s[64][3];
    __shared__ float red_s[8];

    maskf_s[tid] = (float)mask[b * NN + tid];
    if (tid < HD) {
        Ai_s[tid]    = Apre[(b * NN + i) * HD + tid];
        wlast_s[tid] = we1[2 * HD * HD + tid];   // we1 row 2D (dist_sq row)
        wc2_s[tid]   = wc2[tid];
        be2_s[tid]   = be2[tid];
        bc1_s[tid]   = bc1[tid];
        hi_s[tid]    = h[(b * NN + i) * HD + tid];
    }

    const float xi0 = x[(b * NN + i) * 3 + 0];
    const float xi1 = x[(b * NN + i) * 3 + 1];
    const float xi2 = x[(b * NN + i) * 3 + 2];

    // per-wave B fragments in registers: wave owns cols [wv*32, wv*32+32)
    short8 bw2[4][2], bwc[4][2];
    #pragma unroll
    for (int ks = 0; ks < 4; ++ks) {
        #pragma unroll
        for (int nt = 0; nt < 2; ++nt) {
            const int col = wv * 32 + nt * 16 + cl;
            const int off = ((ks * 4 + g) * HD + col) * 8;
            bw2[ks][nt] = *(const short8*)(we2pk + off);
            bwc[ks][nt] = *(const short8*)(wc1pk + off);
        }
    }

    float agg0 = 0.f, agg1 = 0.f;
    float cdx = 0.f, cdy = 0.f, cdz = 0.f;
    const bool act = (mask[b * NN + i] != 0);
    const f32x4 zero4 = {0.f, 0.f, 0.f, 0.f};

    if (act) {
        for (int jc = 0; jc < 4; ++jc) {
            const int j0 = jc * 64;
            // step 1: dist_sq + x_j for this chunk
            if (tid < 64) {
                const int j = j0 + tid;
                const float a0 = x[(b * NN + j) * 3 + 0];
                const float a1 = x[(b * NN + j) * 3 + 1];
                const float a2 = x[(b * NN + j) * 3 + 2];
                xj_s[tid][0] = a0; xj_s[tid][1] = a1; xj_s[tid][2] = a2;
                const float dx = xi0 - a0, dy = xi1 - a1, dz = xi2 - a2;
                d2_s[tid] = dx * dx + dy * dy + dz * dz + 1e-8f;
            }
            __syncthreads();
            // phase A: m1 = silu(A_i + B_j + d2*wlast) -> bf16 tile
            {
                const int jl = tid >> 2;
                const int h0 = (tid & 3) * 32;
                const float d2 = d2_s[jl];
                const float* bp = Bpre + ((size_t)(b * NN + j0 + jl)) * HD + h0;
                unsigned short* dst = tile + jl * TS + h0;
                #pragma unroll
                for (int u = 0; u < 32; u += 8) {
                    const float4 bv0 = *(const float4*)(bp + u);
                    const float4 bv1 = *(const float4*)(bp + u + 4);
                    const float4 av0 = *(const float4*)(&Ai_s[h0 + u]);
                    const float4 av1 = *(const float4*)(&Ai_s[h0 + u + 4]);
                    const float4 wv0 = *(const float4*)(&wlast_s[h0 + u]);
                    const float4 wv1 = *(const float4*)(&wlast_s[h0 + u + 4]);
                    const float v0 = silu(av0.x + bv0.x + d2 * wv0.x);
                    const float v1 = silu(av0.y + bv0.y + d2 * wv0.y);
                    const float v2 = silu(av0.z + bv0.z + d2 * wv0.z);
                    const float v3 = silu(av0.w + bv0.w + d2 * wv0.w);
                    const float v4 = silu(av1.x + bv1.x + d2 * wv1.x);
                    const float v5 = silu(av1.y + bv1.y + d2 * wv1.y);
                    const float v6 = silu(av1.z + bv1.z + d2 * wv1.z);
                    const float v7 = silu(av1.w + bv1.w + d2 * wv1.w);
                    uint4 o;
                    o.x = pk2(v0, v1); o.y = pk2(v2, v3);
                    o.z = pk2(v4, v5); o.w = pk2(v6, v7);
                    *(uint4*)(dst + u) = o;
                }
            }
            __syncthreads();
            // GEMM1: t2 = m1 @ we2
            f32x4 acc[4][2];
            #pragma unroll
            for (int mt = 0; mt < 4; ++mt) { acc[mt][0] = zero4; acc[mt][1] = zero4; }
            #pragma unroll
            for (int ks = 0; ks < 4; ++ks) {
                #pragma unroll
                for (int mt = 0; mt < 4; ++mt) {
                    const short8 a = *(const short8*)(tile + (mt * 16 + cl) * TS + ks * 32 + g * 8);
                    acc[mt][0] = __builtin_amdgcn_mfma_f32_16x16x32_bf16(a, bw2[ks][0], acc[mt][0], 0, 0, 0);
                    acc[mt][1] = __builtin_amdgcn_mfma_f32_16x16x32_bf16(a, bw2[ks][1], acc[mt][1], 0, 0, 0);
                }
            }
            __syncthreads();   // all waves done reading m1
            // epilogue 1: m_ij = silu(t2 + be2) * mask_j ; overwrite tile; agg partials
            #pragma unroll
            for (int nt = 0; nt < 2; ++nt) {
                const int col  = wv * 32 + nt * 16 + cl;
                const float bias = be2_s[col];
                #pragma unroll
                for (int mt = 0; mt < 4; ++mt) {
                    #pragma unroll
                    for (int r = 0; r < 4; ++r) {
                        const int jl = mt * 16 + g * 4 + r;
                        const float mj = maskf_s[j0 + jl];
                        const float v = silu(acc[mt][nt][r] + bias) * mj;
                        if (nt == 0) agg0 += v; else agg1 += v;
                        tile[jl * TS + col] = f2bf(v);
                    }
                }
            }
            __syncthreads();
            // GEMM2: t3 = m_ij @ wc1
            f32x4 acc2[4][2];
            #pragma unroll
            for (int mt = 0; mt < 4; ++mt) { acc2[mt][0] = zero4; acc2[mt][1] = zero4; }
            #pragma unroll
            for (int ks = 0; ks < 4; ++ks) {
                #pragma unroll
                for (int mt = 0; mt < 4; ++mt) {
                    const short8 a = *(const short8*)(tile + (mt * 16 + cl) * TS + ks * 32 + g * 8);
                    acc2[mt][0] = __builtin_amdgcn_mfma_f32_16x16x32_bf16(a, bwc[ks][0], acc2[mt][0], 0, 0, 0);
                    acc2[mt][1] = __builtin_amdgcn_mfma_f32_16x16x32_bf16(a, bwc[ks][1], acc2[mt][1], 0, 0, 0);
                }
            }
            // epilogue 2: s[j] partial = sum_cols silu(t3 + bc1) * wc2
            #pragma unroll
            for (int mt = 0; mt < 4; ++mt) {
                float sp0 = 0.f, sp1 = 0.f, sp2 = 0.f, sp3 = 0.f;
                #pragma unroll
                for (int nt = 0; nt < 2; ++nt) {
                    const int col = wv * 32 + nt * 16 + cl;
                    const float bias = bc1_s[col];
                    const float w2 = wc2_s[col];
                    sp0 += silu(acc2[mt][nt][0] + bias) * w2;
                    sp1 += silu(acc2[mt][nt][1] + bias) * w2;
                    sp2 += silu(acc2[mt][nt][2] + bias) * w2;
                    sp3 += silu(acc2[mt][nt][3] + bias) * w2;
                }
                #pragma unroll
                for (int m = 1; m <= 8; m <<= 1) {
                    sp0 += __shfl_xor(sp0, m); sp1 += __shfl_xor(sp1, m);
                    sp2 += __shfl_xor(sp2, m); sp3 += __shfl_xor(sp3, m);
                }
                if (cl == 0) {
                    const int jb = mt * 16 + g * 4;
                    sws[wv][jb + 0] = sp0; sws[wv][jb + 1] = sp1;
                    sws[wv][jb + 2] = sp2; sws[wv][jb + 3] = sp3;
                }
            }
            __syncthreads();
            // finalize w_ij, accumulate coord partial (per-thread regs)
            if (tid < 64) {
                const float s = sws[0][tid] + sws[1][tid] + sws[2][tid] + sws[3][tid];
                const float w = tanhf(s) * 0.1f * maskf_s[j0 + tid];
                cdx += (xi0 - xj_s[tid][0]) * w;
                cdy += (xi1 - xj_s[tid][1]) * w;
                cdz += (xi2 - xj_s[tid][2]) * w;
            }
        }
    }

    // agg reduce across row-groups (lanes sharing cl)
    agg0 += __shfl_xor(agg0, 16); agg0 += __shfl_xor(agg0, 32);
    agg1 += __shfl_xor(agg1, 16); agg1 += __shfl_xor(agg1, 32);
    if (lane < 16) {
        agg_s[wv * 32 + lane]      = agg0;
        agg_s[wv * 32 + 16 + lane] = agg1;
    }
    if (tid < 64) { cd_s[tid][0] = cdx; cd_s[tid][1] = cdy; cd_s[tid][2] = cdz; }
    __syncthreads();

    if (tid < 3) {
        float s = 0.f;
        for (int t = 0; t < 64; ++t) s += cd_s[t][tid];
        xout[(b * NN + i) * 3 + tid] = x[(b * NN + i) * 3 + tid] + s * (1.f / 256.f);
    }

    // node MLP: h_new = silu([h_i, agg] @ wn1 + bn1) @ wn2 + bn2
    float t4 = 0.f;
    if (tid < HD) {
        t4 = bn1[tid];
        #pragma unroll 4
        for (int k = 0; k < HD; ++k) t4 += hi_s[k] * wn1[k * HD + tid];
        #pragma unroll 4
        for (int k = 0; k < HD; ++k) t4 += agg_s[k] * wn1[(HD + k) * HD + tid];
        s4_s[tid] = silu(t4);
    }
    __syncthreads();
    float h2 = 0.f;
    if (tid < HD) {
        float hn = bn2[tid];
        #pragma unroll 4
        for (int k = 0; k < HD; ++k) hn += s4_s[k] * wn2[k * HD + tid];
        h2 = hi_s[tid] + hn;
    }
    // LayerNorm over 128 (threads >=128 contribute 0)
    float v = (tid < HD) ? h2 : 0.f;
    #pragma unroll
    for (int m = 1; m <= 32; m <<= 1) v += __shfl_xor(v, m);
    if (lane == 0) red_s[wv] = v;
    __syncthreads();
    const float mean = (red_s[0] + red_s[1] + red_s[2] + red_s[3]) * (1.f / 128.f);
    const float dd = (tid < HD) ? (h2 - mean) : 0.f;
    float q = dd * dd;
    #pragma unroll
    for (int m = 1; m <= 32; m <<= 1) q += __shfl_xor(q, m);
    if (lane == 0) red_s[4 + wv] = q;
    __syncthreads();
    const float var = (red_s[4] + red_s[5] + red_s[6] + red_s[7]) * (1.f / 128.f);
    if (tid < HD) {
        hout[(b * NN + i) * HD + tid] = dd * rsqrtf(var + 1e-5f) * gamma[tid] + beta[tid];
    }
}

extern "C" void kernel_launch(void* const* d_in, const int* in_sizes, int n_in,
                              void* d_out, int out_size, void* d_ws, size_t ws_size,
                              hipStream_t stream)
{
    (void)in_sizes; (void)n_in; (void)out_size; (void)ws_size;
    const float* h     = (const float*)d_in[0];
    const float* x     = (const float*)d_in[1];
    const int*   mask  = (const int*)d_in[2];
    const float* we1   = (const float*)d_in[3];
    const float* be1   = (const float*)d_in[4];
    const float* we2   = (const float*)d_in[5];
    const float* be2   = (const float*)d_in[6];
    const float* wn1   = (const float*)d_in[7];
    const float* bn1   = (const float*)d_in[8];
    const float* wn2   = (const float*)d_in[9];
    const float* bn2   = (const float*)d_in[10];
    const float* wc1   = (const float*)d_in[11];
    const float* bc1   = (const float*)d_in[12];
    const float* wc2   = (const float*)d_in[13];
    const float* gamma = (const float*)d_in[14];
    const float* beta  = (const float*)d_in[15];

    float* out  = (float*)d_out;
    float* hout = out;
    float* xout = out + 8 * 256 * 128;

    float* Apre = (float*)d_ws;
    float* Bpre = Apre + 2048 * 128;
    unsigned short* we2pk = (unsigned short*)(Bpre + 2048 * 128);
    unsigned short* wc1pk = we2pk + 128 * 128;

    prep_node<<<2048, 128, 0, stream>>>(h, we1, be1, Apre, Bpre);
    prep_pack<<<64, 256, 0, stream>>>(we2, we2pk);
    prep_pack<<<64, 256, 0, stream>>>(wc1, wc1pk);
    egcl_main<<<2048, 256, 0, stream>>>(h, x, mask, we1, be2, bc1, wc2,
                                        wn1, bn1, wn2, bn2, gamma, beta,
                                        Apre, Bpre, we2pk, wc1pk, hout, xout);
}

// Round 2
// 109.351 us; speedup vs baseline: 1.6744x; 1.6744x over previous
//
#include <hip/hip_runtime.h>
#include <hip/hip_bf16.h>

using short8 = __attribute__((ext_vector_type(8))) short;
using f32x4  = __attribute__((ext_vector_type(4))) float;

#define HD 128
#define NN 256

__device__ __forceinline__ unsigned short us(float v) {
    __hip_bfloat16 b = __float2bfloat16(v);
    union { __hip_bfloat16 b; unsigned short s; } c; c.b = b; return c.s;
}
__device__ __forceinline__ unsigned int pk2(float a, float b) {
    return (unsigned int)us(a) | ((unsigned int)us(b) << 16);
}
__device__ __forceinline__ float silu(float v) { return v / (1.f + __expf(-v)); }
// swizzled LDS byte address for a [rows][128] bf16 tile (256B row stride)
__device__ __forceinline__ int swz(int row, int kbyte) { return row * 256 + (kbyte ^ ((row & 7) << 4)); }
// swizzled LDS byte address for a [rows][256] bf16 tile (512B row stride)
__device__ __forceinline__ int swz512(int row, int kbyte) { return row * 512 + (kbyte ^ ((row & 7) << 4)); }

// ---- prep: A_pre = h @ we1[0:D] + be1 ; B_pre = h @ we1[D:2D] ----
__global__ __launch_bounds__(128) void prep_node(
    const float* __restrict__ h, const float* __restrict__ we1,
    const float* __restrict__ be1, float* __restrict__ Apre, float* __restrict__ Bpre)
{
    const int bn = blockIdx.x;      // 0..2047
    const int t  = threadIdx.x;     // 0..127
    __shared__ float hs[HD];
    hs[t] = h[bn * HD + t];
    __syncthreads();
    float a = be1[t], bb = 0.f;
    #pragma unroll 4
    for (int d = 0; d < HD; ++d) {
        const float hv = hs[d];
        a  += hv * we1[d * HD + t];
        bb += hv * we1[(HD + d) * HD + t];
    }
    Apre[bn * HD + t] = a;
    Bpre[bn * HD + t] = bb;
}

// ---- prep: pack all four [K x 128] fp32 weights -> bf16 MFMA B-fragment layout ----
// pk[((k>>3)*128 + n)*8 + (k&7)] = bf16(w[k][n])
__global__ __launch_bounds__(256) void prep_pack_all(
    const float* __restrict__ we2, const float* __restrict__ wc1,
    const float* __restrict__ wn1, const float* __restrict__ wn2,
    unsigned short* __restrict__ we2pk, unsigned short* __restrict__ wc1pk,
    unsigned short* __restrict__ wn1pk, unsigned short* __restrict__ wn2pk)
{
    const int idx = blockIdx.x * 256 + threadIdx.x;   // 0..81919
    const float* src; unsigned short* dst; int local;
    if (idx < 16384)      { src = we2; dst = we2pk; local = idx; }
    else if (idx < 32768) { src = wc1; dst = wc1pk; local = idx - 16384; }
    else if (idx < 65536) { src = wn1; dst = wn1pk; local = idx - 32768; }
    else                  { src = wn2; dst = wn2pk; local = idx - 65536; }
    const int k = local >> 7, n = local & 127;
    dst[((k >> 3) * 128 + n) * 8 + (k & 7)] = us(src[local]);
}

// ---- prep: per-batch compaction of active j indices ----
__global__ __launch_bounds__(256) void prep_compact(
    const int* __restrict__ mask, int* __restrict__ idxB, int* __restrict__ cntB)
{
    const int b = blockIdx.x, t = threadIdx.x;
    const int lane = t & 63, wv = t >> 6;
    const int m = mask[b * NN + t];
    const unsigned long long bal = __ballot(m != 0);
    const int pos = __popcll(bal & ((1ULL << lane) - 1ULL));
    __shared__ int wc[4];
    if (lane == 0) wc[wv] = __popcll(bal);
    __syncthreads();
    int base = 0;
    for (int w = 0; w < wv; ++w) base += wc[w];
    if (m) idxB[b * NN + base + pos] = t;
    if (t == 0) cntB[b] = wc[0] + wc[1] + wc[2] + wc[3];
}

// ---- main: one block per (b,i) — edge MLPs + coord + agg ----
__global__ __launch_bounds__(256) void egcl_main(
    const float* __restrict__ x, const int* __restrict__ mask,
    const float* __restrict__ we1, const float* __restrict__ be2,
    const float* __restrict__ bc1, const float* __restrict__ wc2,
    const float* __restrict__ Apre, const float* __restrict__ Bpre,
    const unsigned short* __restrict__ we2pk, const unsigned short* __restrict__ wc1pk,
    const int* __restrict__ idxB, const int* __restrict__ cntB,
    float* __restrict__ aggws, float* __restrict__ xout)
{
    const int blk = blockIdx.x;
    const int b = blk >> 8, i = blk & 255;
    const int rowb = b * NN + i;
    const int tid = threadIdx.x;
    const int wv = tid >> 6, lane = tid & 63, g = lane >> 4, cl = lane & 15;

    __shared__ __align__(16) unsigned short tile1[64 * HD];
    __shared__ __align__(16) unsigned short tile2[64 * HD];
    __shared__ int idx_s[NN];
    __shared__ __align__(16) float Ai_s[HD], wlast_s[HD];
    __shared__ float be2_s[HD], bc1_s[HD], wc2_s[HD];
    __shared__ float sws[4][64];

    const int cnt = cntB[b];
    idx_s[tid] = (tid < cnt) ? idxB[b * NN + tid] : 0;
    if (tid < HD) {
        Ai_s[tid]    = Apre[rowb * HD + tid];
        wlast_s[tid] = we1[2 * HD * HD + tid];
        be2_s[tid]   = be2[tid];
        bc1_s[tid]   = bc1[tid];
        wc2_s[tid]   = wc2[tid];
    }

    // per-wave B fragments in registers: wave owns cols [wv*32, wv*32+32)
    short8 bw2[4][2], bwc[4][2];
    #pragma unroll
    for (int ks = 0; ks < 4; ++ks) {
        #pragma unroll
        for (int nt = 0; nt < 2; ++nt) {
            const int col = wv * 32 + nt * 16 + cl;
            const int off = ((ks * 4 + g) * HD + col) * 8;
            bw2[ks][nt] = *(const short8*)(we2pk + off);
            bwc[ks][nt] = *(const short8*)(wc1pk + off);
        }
    }

    const float xi0 = x[rowb * 3 + 0];
    const float xi1 = x[rowb * 3 + 1];
    const float xi2 = x[rowb * 3 + 2];
    const bool act = (mask[rowb] != 0);
    float agg0 = 0.f, agg1 = 0.f, cdx = 0.f, cdy = 0.f, cdz = 0.f;
    const f32x4 zero4 = {0.f, 0.f, 0.f, 0.f};
    __syncthreads();

    const int nch = act ? ((cnt + 63) >> 6) : 0;
    for (int jc = 0; jc < nch; ++jc) {
        const int j0 = jc * 64;
        // ---- phase A: m1 = silu(A_i + B_j + d2*wlast) -> bf16 tile1 (swizzled) ----
        {
            const int jl = tid >> 2;
            const int j  = idx_s[j0 + jl];          // j0+jl <= 255, pad entries -> j=0 (zeroed later)
            const int h0 = (tid & 3) * 32;
            const float* xj = x + (b * NN + j) * 3;
            const float dx = xi0 - xj[0], dy = xi1 - xj[1], dz = xi2 - xj[2];
            const float d2 = dx * dx + dy * dy + dz * dz + 1e-8f;
            const float* bp = Bpre + (size_t)(b * NN + j) * HD + h0;
            char* dst = (char*)tile1;
            #pragma unroll
            for (int u = 0; u < 32; u += 8) {
                const float4 bv0 = *(const float4*)(bp + u);
                const float4 bv1 = *(const float4*)(bp + u + 4);
                const float4 av0 = *(const float4*)(&Ai_s[h0 + u]);
                const float4 av1 = *(const float4*)(&Ai_s[h0 + u + 4]);
                const float4 wv0 = *(const float4*)(&wlast_s[h0 + u]);
                const float4 wv1 = *(const float4*)(&wlast_s[h0 + u + 4]);
                uint4 o;
                o.x = pk2(silu(av0.x + bv0.x + d2 * wv0.x), silu(av0.y + bv0.y + d2 * wv0.y));
                o.y = pk2(silu(av0.z + bv0.z + d2 * wv0.z), silu(av0.w + bv0.w + d2 * wv0.w));
                o.z = pk2(silu(av1.x + bv1.x + d2 * wv1.x), silu(av1.y + bv1.y + d2 * wv1.y));
                o.w = pk2(silu(av1.z + bv1.z + d2 * wv1.z), silu(av1.w + bv1.w + d2 * wv1.w));
                *(uint4*)(dst + swz(jl, 2 * (h0 + u))) = o;
            }
        }
        __syncthreads();
        // ---- GEMM1: t2 = m1 @ we2 ----
        f32x4 acc[4][2];
        #pragma unroll
        for (int mt = 0; mt < 4; ++mt) { acc[mt][0] = zero4; acc[mt][1] = zero4; }
        #pragma unroll
        for (int ks = 0; ks < 4; ++ks) {
            #pragma unroll
            for (int mt = 0; mt < 4; ++mt) {
                const short8 a = *(const short8*)((char*)tile1 + swz(mt * 16 + cl, ks * 64 + g * 16));
                acc[mt][0] = __builtin_amdgcn_mfma_f32_16x16x32_bf16(a, bw2[ks][0], acc[mt][0], 0, 0, 0);
                acc[mt][1] = __builtin_amdgcn_mfma_f32_16x16x32_bf16(a, bw2[ks][1], acc[mt][1], 0, 0, 0);
            }
        }
        // ---- epilogue 1: m_ij = silu(t2 + be2) (pad rows zeroed) -> tile2; agg partials ----
        #pragma unroll
        for (int nt = 0; nt < 2; ++nt) {
            const int col = wv * 32 + nt * 16 + cl;
            const float bias = be2_s[col];
            #pragma unroll
            for (int mt = 0; mt < 4; ++mt) {
                #pragma unroll
                for (int r = 0; r < 4; ++r) {
                    const int jl = mt * 16 + g * 4 + r;
                    const float mp = (j0 + jl < cnt) ? 1.f : 0.f;
                    const float v = silu(acc[mt][nt][r] + bias) * mp;
                    if (nt == 0) agg0 += v; else agg1 += v;
                    *(unsigned short*)((char*)tile2 + swz(jl, 2 * col)) = us(v);
                }
            }
        }
        __syncthreads();
        // ---- GEMM2: t3 = m_ij @ wc1 ----
        f32x4 acc2[4][2];
        #pragma unroll
        for (int mt = 0; mt < 4; ++mt) { acc2[mt][0] = zero4; acc2[mt][1] = zero4; }
        #pragma unroll
        for (int ks = 0; ks < 4; ++ks) {
            #pragma unroll
            for (int mt = 0; mt < 4; ++mt) {
                const short8 a = *(const short8*)((char*)tile2 + swz(mt * 16 + cl, ks * 64 + g * 16));
                acc2[mt][0] = __builtin_amdgcn_mfma_f32_16x16x32_bf16(a, bwc[ks][0], acc2[mt][0], 0, 0, 0);
                acc2[mt][1] = __builtin_amdgcn_mfma_f32_16x16x32_bf16(a, bwc[ks][1], acc2[mt][1], 0, 0, 0);
            }
        }
        // ---- epilogue 2: s[j] = sum_cols silu(t3 + bc1) * wc2 ----
        #pragma unroll
        for (int mt = 0; mt < 4; ++mt) {
            float sp0 = 0.f, sp1 = 0.f, sp2 = 0.f, sp3 = 0.f;
            #pragma unroll
            for (int nt = 0; nt < 2; ++nt) {
                const int col = wv * 32 + nt * 16 + cl;
                const float bias = bc1_s[col];
                const float w2 = wc2_s[col];
                sp0 += silu(acc2[mt][nt][0] + bias) * w2;
                sp1 += silu(acc2[mt][nt][1] + bias) * w2;
                sp2 += silu(acc2[mt][nt][2] + bias) * w2;
                sp3 += silu(acc2[mt][nt][3] + bias) * w2;
            }
            #pragma unroll
            for (int m = 1; m <= 8; m <<= 1) {
                sp0 += __shfl_xor(sp0, m); sp1 += __shfl_xor(sp1, m);
                sp2 += __shfl_xor(sp2, m); sp3 += __shfl_xor(sp3, m);
            }
            if (cl == 0) {
                const int jb = mt * 16 + g * 4;
                sws[wv][jb + 0] = sp0; sws[wv][jb + 1] = sp1;
                sws[wv][jb + 2] = sp2; sws[wv][jb + 3] = sp3;
            }
        }
        __syncthreads();
        // ---- finalize w_ij, accumulate coord partials (wave 0) ----
        if (tid < 64) {
            const int p = j0 + tid;
            const float s = sws[0][tid] + sws[1][tid] + sws[2][tid] + sws[3][tid];
            const float w = tanhf(s) * 0.1f * ((p < cnt) ? 1.f : 0.f);
            const int j = idx_s[p];
            const float* xj = x + (b * NN + j) * 3;
            cdx += (xi0 - xj[0]) * w;
            cdy += (xi1 - xj[1]) * w;
            cdz += (xi2 - xj[2]) * w;
        }
    }

    // agg reduce across g-groups and store to workspace
    agg0 += __shfl_xor(agg0, 16); agg0 += __shfl_xor(agg0, 32);
    agg1 += __shfl_xor(agg1, 16); agg1 += __shfl_xor(agg1, 32);
    if (lane < 16) {
        aggws[rowb * HD + wv * 32 + lane]      = agg0;
        aggws[rowb * HD + wv * 32 + 16 + lane] = agg1;
    }
    // coord reduce (wave 0) and store
    if (tid < 64) {
        #pragma unroll
        for (int m = 1; m <= 32; m <<= 1) {
            cdx += __shfl_xor(cdx, m);
            cdy += __shfl_xor(cdy, m);
            cdz += __shfl_xor(cdz, m);
        }
        if (tid == 0) {
            xout[rowb * 3 + 0] = xi0 + cdx * (1.f / 256.f);
            xout[rowb * 3 + 1] = xi1 + cdy * (1.f / 256.f);
            xout[rowb * 3 + 2] = xi2 + cdz * (1.f / 256.f);
        }
    }
}

// ---- node MLP + LayerNorm: 16 rows per block, MFMA ----
__global__ __launch_bounds__(256) void node_mlp(
    const float* __restrict__ h, const float* __restrict__ aggws,
    const unsigned short* __restrict__ wn1pk, const unsigned short* __restrict__ wn2pk,
    const float* __restrict__ bn1, const float* __restrict__ bn2,
    const float* __restrict__ gamma, const float* __restrict__ beta,
    float* __restrict__ hout)
{
    const int r0 = blockIdx.x * 16;                 // rows are flattened (b*N+i)
    const int tid = threadIdx.x;
    const int wv = tid >> 6, lane = tid & 63, g = lane >> 4, cl = lane & 15;
    __shared__ __align__(16) unsigned short t1[16 * 256];
    __shared__ __align__(16) unsigned short t2[16 * HD];
    __shared__ float rs1[4][16], rs2[4][16];
    __shared__ float bn1_s[HD], bn2_s[HD], gam_s[HD], bet_s[HD];
    if (tid < HD) {
        bn1_s[tid] = bn1[tid]; bn2_s[tid] = bn2[tid];
        gam_s[tid] = gamma[tid]; bet_s[tid] = beta[tid];
    }
    // stage A tile: [16 rows][256 k] = [h | agg] in bf16, swizzled
    {
        const int row = tid >> 4, k0 = (tid & 15) * 16;
        const float* src = (k0 < HD) ? (h + (size_t)(r0 + row) * HD + k0)
                                     : (aggws + (size_t)(r0 + row) * HD + (k0 - HD));
        char* dst = (char*)t1;
        #pragma unroll
        for (int u = 0; u < 16; u += 8) {
            const float4 a0 = *(const float4*)(src + u);
            const float4 a1 = *(const float4*)(src + u + 4);
            uint4 o;
            o.x = pk2(a0.x, a0.y); o.y = pk2(a0.z, a0.w);
            o.z = pk2(a1.x, a1.y); o.w = pk2(a1.z, a1.w);
            *(uint4*)(dst + swz512(row, 2 * (k0 + u))) = o;
        }
    }
    __syncthreads();
    const f32x4 zero4 = {0.f, 0.f, 0.f, 0.f};
    // GEMM1: [16x256] @ wn1
    f32x4 acc[2] = {zero4, zero4};
    #pragma unroll
    for (int ks = 0; ks < 8; ++ks) {
        const short8 a = *(const short8*)((char*)t1 + swz512(cl, ks * 64 + g * 16));
        #pragma unroll
        for (int nt = 0; nt < 2; ++nt) {
            const int col = wv * 32 + nt * 16 + cl;
            const short8 bb = *(const short8*)(wn1pk + ((ks * 4 + g) * HD + col) * 8);
            acc[nt] = __builtin_amdgcn_mfma_f32_16x16x32_bf16(a, bb, acc[nt], 0, 0, 0);
        }
    }
    // epilogue 1: silu -> t2
    #pragma unroll
    for (int nt = 0; nt < 2; ++nt) {
        const int col = wv * 32 + nt * 16 + cl;
        const float bias = bn1_s[col];
        #pragma unroll
        for (int r = 0; r < 4; ++r) {
            const int row = g * 4 + r;
            *(unsigned short*)((char*)t2 + swz(row, 2 * col)) = us(silu(acc[nt][r] + bias));
        }
    }
    __syncthreads();
    // GEMM2: [16x128] @ wn2
    f32x4 acc2[2] = {zero4, zero4};
    #pragma unroll
    for (int ks = 0; ks < 4; ++ks) {
        const short8 a = *(const short8*)((char*)t2 + swz(cl, ks * 64 + g * 16));
        #pragma unroll
        for (int nt = 0; nt < 2; ++nt) {
            const int col = wv * 32 + nt * 16 + cl;
            const short8 bb = *(const short8*)(wn2pk + ((ks * 4 + g) * HD + col) * 8);
            acc2[nt] = __builtin_amdgcn_mfma_f32_16x16x32_bf16(a, bb, acc2[nt], 0, 0, 0);
        }
    }
    // residual (fp32 h from global)
    float h2[2][4];
    #pragma unroll
    for (int nt = 0; nt < 2; ++nt) {
        const int col = wv * 32 + nt * 16 + cl;
        #pragma unroll
        for (int r = 0; r < 4; ++r) {
            const int row = g * 4 + r;
            h2[nt][r] = acc2[nt][r] + bn2_s[col] + h[(size_t)(r0 + row) * HD + col];
        }
    }
    // LayerNorm over 128 cols per row
    #pragma unroll
    for (int r = 0; r < 4; ++r) {
        float p = h2[0][r] + h2[1][r];
        p += __shfl_xor(p, 1); p += __shfl_xor(p, 2);
        p += __shfl_xor(p, 4); p += __shfl_xor(p, 8);
        if (cl == 0) rs1[wv][g * 4 + r] = p;
    }
    __syncthreads();
    float mean[4];
    #pragma unroll
    for (int r = 0; r < 4; ++r) {
        const int row = g * 4 + r;
        mean[r] = (rs1[0][row] + rs1[1][row] + rs1[2][row] + rs1[3][row]) * (1.f / HD);
    }
    #pragma unroll
    for (int r = 0; r < 4; ++r) {
        const float d0 = h2[0][r] - mean[r], d1 = h2[1][r] - mean[r];
        float q = d0 * d0 + d1 * d1;
        q += __shfl_xor(q, 1); q += __shfl_xor(q, 2);
        q += __shfl_xor(q, 4); q += __shfl_xor(q, 8);
        if (cl == 0) rs2[wv][g * 4 + r] = q;
    }
    __syncthreads();
    #pragma unroll
    for (int r = 0; r < 4; ++r) {
        const int row = g * 4 + r;
        const float var = (rs2[0][row] + rs2[1][row] + rs2[2][row] + rs2[3][row]) * (1.f / HD);
        const float rsq = rsqrtf(var + 1e-5f);
        #pragma unroll
        for (int nt = 0; nt < 2; ++nt) {
            const int col = wv * 32 + nt * 16 + cl;
            hout[(size_t)(r0 + row) * HD + col] = (h2[nt][r] - mean[r]) * rsq * gam_s[col] + bet_s[col];
        }
    }
}

extern "C" void kernel_launch(void* const* d_in, const int* in_sizes, int n_in,
                              void* d_out, int out_size, void* d_ws, size_t ws_size,
                              hipStream_t stream)
{
    (void)in_sizes; (void)n_in; (void)out_size; (void)ws_size;
    const float* h     = (const float*)d_in[0];
    const float* x     = (const float*)d_in[1];
    const int*   mask  = (const int*)d_in[2];
    const float* we1   = (const float*)d_in[3];
    const float* be1   = (const float*)d_in[4];
    const float* we2   = (const float*)d_in[5];
    const float* be2   = (const float*)d_in[6];
    const float* wn1   = (const float*)d_in[7];
    const float* bn1   = (const float*)d_in[8];
    const float* wn2   = (const float*)d_in[9];
    const float* bn2   = (const float*)d_in[10];
    const float* wc1   = (const float*)d_in[11];
    const float* bc1   = (const float*)d_in[12];
    const float* wc2   = (const float*)d_in[13];
    const float* gamma = (const float*)d_in[14];
    const float* beta  = (const float*)d_in[15];

    float* out  = (float*)d_out;
    float* hout = out;
    float* xout = out + 8 * 256 * 128;

    float* Apre  = (float*)d_ws;
    float* Bpre  = Apre + 2048 * 128;
    float* aggws = Bpre + 2048 * 128;
    unsigned short* we2pk = (unsigned short*)(aggws + 2048 * 128);
    unsigned short* wc1pk = we2pk + 128 * 128;
    unsigned short* wn1pk = wc1pk + 128 * 128;
    unsigned short* wn2pk = wn1pk + 256 * 128;
    int* idxB = (int*)(wn2pk + 128 * 128);
    int* cntB = idxB + 8 * 256;

    prep_node<<<2048, 128, 0, stream>>>(h, we1, be1, Apre, Bpre);
    prep_pack_all<<<320, 256, 0, stream>>>(we2, wc1, wn1, wn2, we2pk, wc1pk, wn1pk, wn2pk);
    prep_compact<<<8, 256, 0, stream>>>(mask, idxB, cntB);
    egcl_main<<<2048, 256, 0, stream>>>(x, mask, we1, be2, bc1, wc2,
                                        Apre, Bpre, we2pk, wc1pk, idxB, cntB,
                                        aggws, xout);
    node_mlp<<<128, 256, 0, stream>>>(h, aggws, wn1pk, wn2pk, bn1, bn2, gamma, beta, hout);
}